// Round 6
// baseline (143.685 us; speedup 1.0000x reference)
//
#include <hip/hip_runtime.h>
#include <stdint.h>

#define NNODE 1000
#define KSP   200
#define DIM   64
#define BATCH 8
#define WPB   4      // waves per block
#define NPW   4      // nodes per wave (pipeline depth)
#define NBLK  ((BATCH * NNODE) / (WPB * NPW))   // 500 blocks

__global__ __launch_bounds__(256) void knn_edge_kernel(
    const float* __restrict__ locs,   // [B, N, 2]
    const float* __restrict__ emb,    // [B, N, 64]
    const float* __restrict__ W,      // [64]
    const float* __restrict__ bias,   // [64]
    float* __restrict__ out)
{
    __shared__ int      hist[WPB][256];   // 4 KB
    __shared__ uint64_t cand[WPB][256];   // 8 KB
    __shared__ int      cnts[WPB], ssp[WPB];

    const int tid  = threadIdx.x;
    const int w    = tid >> 6;
    const int lane = tid & 63;
    const int wgid = blockIdx.x * WPB + w;     // 0 .. 1999

    const size_t E = (size_t)BATCH * NNODE * KSP;
    float* x_out = out;
    float* ei0   = out + (size_t)BATCH * NNODE * DIM;
    float* ei1   = ei0 + E;
    float* eemb  = ei1 + E;

    // per-lane W/bias registers (channel group invariant across store loop)
    const int c4 = (lane & 15) << 2;
    const float4 w4 = *(const float4*)(W + c4);
    const float4 b4 = *(const float4*)(bias + c4);

    for (int p = 0; p < NPW; ++p) {
        const int node = wgid * NPW + p;       // 0 .. 7999, contiguous per wave
        const int b    = node / NNODE;
        const int i    = node - b * NNODE;

        #pragma unroll
        for (int c = 0; c < 4; ++c) hist[w][c * 64 + lane] = 0;
        if (lane == 0) { cnts[w] = 0; ssp[w] = KSP + 1; }
        __builtin_amdgcn_wave_barrier();

        const float2* loc = (const float2*)(locs + (size_t)b * NNODE * 2);
        const float2 self = loc[i];

        // ---- pass 1: distances (exact XLA rounding) + per-wave histogram ----
        for (int j = lane; j < NNODE; j += 64) {
            float2 pt = loc[j];
            float dx = __fsub_rn(self.x, pt.x);
            float dy = __fsub_rn(self.y, pt.y);
            float d  = __fsqrt_rn(__fadd_rn(__fmul_rn(dx, dx), __fmul_rn(dy, dy)));
            int q = (int)(d * 180.0f);
            q = q > 255 ? 255 : q;
            atomicAdd(&hist[w][q], 1);
        }
        __builtin_amdgcn_wave_barrier();

        // ---- shfl inclusive scan over 256 bins; smallest bin B with cum >= 201 ----
        int base = 0, Bcand = 1 << 30;
        #pragma unroll
        for (int c = 0; c < 4; ++c) {
            int sc = hist[w][c * 64 + lane];
            #pragma unroll
            for (int off = 1; off < 64; off <<= 1) {
                int y = __shfl_up(sc, off, 64);
                if (lane >= off) sc += y;
            }
            int cum = sc + base;
            if (cum >= KSP + 1 && Bcand == (1 << 30)) Bcand = c * 64 + lane;
            base += __shfl(sc, 63, 64);
        }
        #pragma unroll
        for (int off = 32; off; off >>= 1) Bcand = min(Bcand, __shfl_xor(Bcand, off, 64));
        const int B = Bcand;

        // ---- pass 2: gather candidates with q <= B ----
        for (int j = lane; j < NNODE; j += 64) {
            float2 pt = loc[j];
            float dx = __fsub_rn(self.x, pt.x);
            float dy = __fsub_rn(self.y, pt.y);
            float d  = __fsqrt_rn(__fadd_rn(__fmul_rn(dx, dx), __fmul_rn(dy, dy)));
            int q = (int)(d * 180.0f);
            q = q > 255 ? 255 : q;
            if (q <= B) {
                int pos = atomicAdd(&cnts[w], 1);
                if (pos < 256) cand[w][pos] = ((uint64_t)__float_as_uint(d) << 32) | (uint32_t)j;
            }
        }
        __builtin_amdgcn_wave_barrier();
        const int cnt = min(cnts[w], 256);
        for (int t = cnt + lane; t < 256; t += 64) cand[w][t] = ~0ull;   // pad
        __builtin_amdgcn_wave_barrier();

        // ---- register bitonic sort: 256 keys, 4 per lane, e = lane*4 + r ----
        uint64_t val[4];
        #pragma unroll
        for (int r = 0; r < 4; ++r) val[r] = cand[w][(lane << 2) | r];

        for (int size = 2; size <= 256; size <<= 1) {
            for (int s = size >> 1; s > 0; s >>= 1) {
                if (s >= 4) {
                    int lmask = s >> 2;
                    #pragma unroll
                    for (int r = 0; r < 4; ++r) {
                        uint64_t other = __shfl_xor(val[r], lmask, 64);
                        int e = (lane << 2) | r;
                        bool up  = ((e & size) == 0);
                        bool low = ((e & s) == 0);
                        uint64_t mn = val[r] < other ? val[r] : other;
                        uint64_t mx = val[r] < other ? other : val[r];
                        val[r] = (up == low) ? mn : mx;
                    }
                } else {
                    #pragma unroll
                    for (int r = 0; r < 4; ++r) {
                        if ((r & s) == 0) {
                            int r2 = r | s;
                            int e = (lane << 2) | r;
                            bool up = ((e & size) == 0);
                            uint64_t a = val[r], c2 = val[r2];
                            bool sw = up ? (a > c2) : (a < c2);
                            if (sw) { val[r] = c2; val[r2] = a; }
                        }
                    }
                }
            }
        }

        // ---- write back sorted first 201; locate self ----
        #pragma unroll
        for (int r = 0; r < 4; ++r) {
            int e = (lane << 2) | r;
            if (e <= KSP) cand[w][e] = val[r];
        }
        __builtin_amdgcn_wave_barrier();
        for (int t = lane; t <= KSP; t += 64) {
            if ((uint32_t)cand[w][t] == (uint32_t)i) atomicMin(&ssp[w], t);
        }
        __builtin_amdgcn_wave_barrier();
        const int sp = ssp[w];

        // ---- outputs ----
        x_out[(size_t)node * DIM + lane] = emb[(size_t)node * DIM + lane];

        const size_t ebase = (size_t)node * KSP;
        for (int t = lane; t < KSP; t += 64) {
            int slot = t + (t >= sp ? 1 : 0);
            uint64_t kk = cand[w][slot];
            ei0[ebase + t] = (float)node;
            ei1[ebase + t] = (float)(b * NNODE + (int)(uint32_t)kk);
        }

        float4* em4 = (float4*)(eemb + ebase * DIM);
        for (int t = lane; t < KSP * (DIM / 4); t += 64) {
            int e    = t >> 4;
            int slot = e + (e >= sp ? 1 : 0);
            float d = __uint_as_float((uint32_t)(cand[w][slot] >> 32));
            float4 v;
            v.x = fmaf(d, w4.x, b4.x);
            v.y = fmaf(d, w4.y, b4.y);
            v.z = fmaf(d, w4.z, b4.z);
            v.w = fmaf(d, w4.w, b4.w);
            em4[t] = v;
        }
        // next node's LDS writes are program-ordered after this node's LDS reads
        __builtin_amdgcn_wave_barrier();
    }
}

extern "C" void kernel_launch(void* const* d_in, const int* in_sizes, int n_in,
                              void* d_out, int out_size, void* d_ws, size_t ws_size,
                              hipStream_t stream) {
    const float* locs = (const float*)d_in[0];
    const float* emb  = (const float*)d_in[1];
    const float* W    = (const float*)d_in[2];
    const float* bias = (const float*)d_in[3];
    float* out = (float*)d_out;

    knn_edge_kernel<<<NBLK, 256, 0, stream>>>(locs, emb, W, bias, out);
}

// Round 7
// 120.814 us; speedup vs baseline: 1.1893x; 1.1893x over previous
//
#include <hip/hip_runtime.h>
#include <stdint.h>

#define NNODE 1000
#define KSP   200
#define DIM   64
#define BATCH 8
#define WPB   4      // waves per block (K1)
#define NN    (BATCH * NNODE)          // 8000 nodes
#define NE    (NN * KSP)               // 1,600,000 edges

// ---------------- K1: KNN selection -> compact ws ----------------
__global__ __launch_bounds__(256) void knn_select_kernel(
    const float* __restrict__ locs,   // [B, N, 2]
    float* __restrict__ dS,           // [NE] sorted distances
    float* __restrict__ nF)           // [NE] neighbor global id as float
{
    __shared__ int      hist[WPB][256];
    __shared__ uint64_t cand[WPB][256];
    __shared__ int      cnts[WPB], ssp[WPB];

    const int tid  = threadIdx.x;
    const int w    = tid >> 6;
    const int lane = tid & 63;
    const int node = blockIdx.x * WPB + w;     // 0 .. 7999
    const int b    = node / NNODE;
    const int i    = node - b * NNODE;

    #pragma unroll
    for (int c = 0; c < 4; ++c) hist[w][c * 64 + lane] = 0;
    if (lane == 0) { cnts[w] = 0; ssp[w] = KSP + 1; }
    __builtin_amdgcn_wave_barrier();

    const float2* loc = (const float2*)(locs + (size_t)b * NNODE * 2);
    const float2 self = loc[i];

    // pass 1: distances (exact XLA rounding) + per-wave histogram
    for (int j = lane; j < NNODE; j += 64) {
        float2 pt = loc[j];
        float dx = __fsub_rn(self.x, pt.x);
        float dy = __fsub_rn(self.y, pt.y);
        float d  = __fsqrt_rn(__fadd_rn(__fmul_rn(dx, dx), __fmul_rn(dy, dy)));
        int q = (int)(d * 180.0f);
        q = q > 255 ? 255 : q;
        atomicAdd(&hist[w][q], 1);
    }
    __builtin_amdgcn_wave_barrier();

    // shfl inclusive scan over 256 bins; smallest bin B with cum >= 201
    int base = 0, Bcand = 1 << 30;
    #pragma unroll
    for (int c = 0; c < 4; ++c) {
        int sc = hist[w][c * 64 + lane];
        #pragma unroll
        for (int off = 1; off < 64; off <<= 1) {
            int y = __shfl_up(sc, off, 64);
            if (lane >= off) sc += y;
        }
        int cum = sc + base;
        if (cum >= KSP + 1 && Bcand == (1 << 30)) Bcand = c * 64 + lane;
        base += __shfl(sc, 63, 64);
    }
    #pragma unroll
    for (int off = 32; off; off >>= 1) Bcand = min(Bcand, __shfl_xor(Bcand, off, 64));
    const int B = Bcand;

    // pass 2: gather candidates with q <= B
    for (int j = lane; j < NNODE; j += 64) {
        float2 pt = loc[j];
        float dx = __fsub_rn(self.x, pt.x);
        float dy = __fsub_rn(self.y, pt.y);
        float d  = __fsqrt_rn(__fadd_rn(__fmul_rn(dx, dx), __fmul_rn(dy, dy)));
        int q = (int)(d * 180.0f);
        q = q > 255 ? 255 : q;
        if (q <= B) {
            int pos = atomicAdd(&cnts[w], 1);
            if (pos < 256) cand[w][pos] = ((uint64_t)__float_as_uint(d) << 32) | (uint32_t)j;
        }
    }
    __builtin_amdgcn_wave_barrier();
    const int cnt = min(cnts[w], 256);
    for (int t = cnt + lane; t < 256; t += 64) cand[w][t] = ~0ull;
    __builtin_amdgcn_wave_barrier();

    // register bitonic sort: 256 keys, 4 per lane, e = lane*4 + r
    uint64_t val[4];
    #pragma unroll
    for (int r = 0; r < 4; ++r) val[r] = cand[w][(lane << 2) | r];

    for (int size = 2; size <= 256; size <<= 1) {
        for (int s = size >> 1; s > 0; s >>= 1) {
            if (s >= 4) {
                int lmask = s >> 2;
                #pragma unroll
                for (int r = 0; r < 4; ++r) {
                    uint64_t other = __shfl_xor(val[r], lmask, 64);
                    int e = (lane << 2) | r;
                    bool up  = ((e & size) == 0);
                    bool low = ((e & s) == 0);
                    uint64_t mn = val[r] < other ? val[r] : other;
                    uint64_t mx = val[r] < other ? other : val[r];
                    val[r] = (up == low) ? mn : mx;
                }
            } else {
                #pragma unroll
                for (int r = 0; r < 4; ++r) {
                    if ((r & s) == 0) {
                        int r2 = r | s;
                        int e = (lane << 2) | r;
                        bool up = ((e & size) == 0);
                        uint64_t a = val[r], c2 = val[r2];
                        bool sw = up ? (a > c2) : (a < c2);
                        if (sw) { val[r] = c2; val[r2] = a; }
                    }
                }
            }
        }
    }

    // write back sorted first 201; locate self
    #pragma unroll
    for (int r = 0; r < 4; ++r) {
        int e = (lane << 2) | r;
        if (e <= KSP) cand[w][e] = val[r];
    }
    __builtin_amdgcn_wave_barrier();
    for (int t = lane; t <= KSP; t += 64) {
        if ((uint32_t)cand[w][t] == (uint32_t)i) atomicMin(&ssp[w], t);
    }
    __builtin_amdgcn_wave_barrier();
    const int sp = ssp[w];

    // compact outputs: d and neighbor (global id) as float
    const size_t ebase = (size_t)node * KSP;
    for (int t = lane; t < KSP; t += 64) {
        int slot = t + (t >= sp ? 1 : 0);
        uint64_t kk = cand[w][slot];
        dS[ebase + t] = __uint_as_float((uint32_t)(kk >> 32));
        nF[ebase + t] = (float)(b * NNODE + (int)(uint32_t)kk);
    }
    __builtin_amdgcn_wave_barrier();
}

// ---------------- K2: fill-like streamer over the whole output ----------------
#define X4    (NN * DIM / 4)           // 128,000
#define EI04  (X4 + NE / 4)            // 528,000
#define EI14  (EI04 + NE / 4)          // 928,000
#define TOT4  (EI14 + NE * DIM / 4)    // 26,528,000

__global__ __launch_bounds__(256) void stream_out_kernel(
    const float* __restrict__ emb,    // [NN, 64]
    const float* __restrict__ W,      // [64]
    const float* __restrict__ bias,   // [64]
    const float* __restrict__ dS,     // [NE]
    const float* __restrict__ nF,     // [NE]
    float4* __restrict__ out4)
{
    const int n = blockIdx.x * 256 + threadIdx.x;   // < TOT4

    if (n >= EI14) {
        // edge_emb
        int t4 = n - EI14;
        int e  = t4 >> 4;
        int c4 = (t4 & 15) << 2;
        float d = dS[e];
        const float4 w4 = *(const float4*)(W + c4);
        const float4 b4 = *(const float4*)(bias + c4);
        float4 v;
        v.x = fmaf(d, w4.x, b4.x);
        v.y = fmaf(d, w4.y, b4.y);
        v.z = fmaf(d, w4.z, b4.z);
        v.w = fmaf(d, w4.w, b4.w);
        out4[n] = v;
    } else if (n < X4) {
        out4[n] = ((const float4*)emb)[n];
    } else if (n < EI04) {
        int e0 = (n - X4) << 2;
        float4 v;
        v.x = (float)((e0 + 0) / KSP);
        v.y = (float)((e0 + 1) / KSP);
        v.z = (float)((e0 + 2) / KSP);
        v.w = (float)((e0 + 3) / KSP);
        out4[n] = v;
    } else {
        out4[n] = ((const float4*)nF)[n - EI04];
    }
}

extern "C" void kernel_launch(void* const* d_in, const int* in_sizes, int n_in,
                              void* d_out, int out_size, void* d_ws, size_t ws_size,
                              hipStream_t stream) {
    const float* locs = (const float*)d_in[0];
    const float* emb  = (const float*)d_in[1];
    const float* W    = (const float*)d_in[2];
    const float* bias = (const float*)d_in[3];

    float* dS = (float*)d_ws;               // 6.4 MB
    float* nF = dS + NE;                    // 6.4 MB

    knn_select_kernel<<<NN / WPB, 256, 0, stream>>>(locs, dS, nF);
    stream_out_kernel<<<TOT4 / 256, 256, 0, stream>>>(emb, W, bias, dS, nF, (float4*)d_out);
}

// Round 8
// 101.812 us; speedup vs baseline: 1.4113x; 1.1866x over previous
//
#include <hip/hip_runtime.h>
#include <stdint.h>

#define NNODE 1000
#define KSP   200
#define DIM   64
#define BATCH 8
#define WPB   4      // waves (nodes) per block

__global__ __launch_bounds__(256) void knn_edge_kernel(
    const float* __restrict__ locs,   // [B, N, 2]
    const float* __restrict__ emb,    // [B, N, 64]
    const float* __restrict__ W,      // [64]
    const float* __restrict__ bias,   // [64]
    float* __restrict__ out)
{
    __shared__ int      hist[WPB][256];   // bins -> excl starts -> fill cursors -> ends
    __shared__ uint64_t cand[WPB][256];   // counting-sorted keys, then rank-permuted
    __shared__ int      ssp[WPB];

    const int tid  = threadIdx.x;
    const int w    = tid >> 6;
    const int lane = tid & 63;
    const int node = blockIdx.x * WPB + w;     // 0 .. 7999
    const int b    = node / NNODE;
    const int i    = node - b * NNODE;

    #pragma unroll
    for (int c = 0; c < 4; ++c) hist[w][c * 64 + lane] = 0;
    if (lane == 0) ssp[w] = KSP + 1;
    __builtin_amdgcn_wave_barrier();

    const float2* loc = (const float2*)(locs + (size_t)b * NNODE * 2);
    const float2 self = loc[i];

    // ---- pass 1: distances (exact XLA rounding) + histogram ----
    for (int j = lane; j < NNODE; j += 64) {
        float2 pt = loc[j];
        float dx = __fsub_rn(self.x, pt.x);
        float dy = __fsub_rn(self.y, pt.y);
        float d  = __fsqrt_rn(__fadd_rn(__fmul_rn(dx, dx), __fmul_rn(dy, dy)));
        int q = (int)(d * 180.0f);
        q = q > 255 ? 255 : q;
        atomicAdd(&hist[w][q], 1);
    }
    __builtin_amdgcn_wave_barrier();

    // ---- scan: pick bin B (cum >= 201); hist <- exclusive bin starts ----
    int base = 0, Bcand = 1 << 30;
    #pragma unroll
    for (int c = 0; c < 4; ++c) {
        int x  = hist[w][c * 64 + lane];
        int sc = x;
        #pragma unroll
        for (int off = 1; off < 64; off <<= 1) {
            int y = __shfl_up(sc, off, 64);
            if (lane >= off) sc += y;
        }
        int cum = sc + base;                       // inclusive
        if (cum >= KSP + 1 && Bcand == (1 << 30)) Bcand = c * 64 + lane;
        hist[w][c * 64 + lane] = cum - x;          // exclusive start
        base += __shfl(sc, 63, 64);
    }
    #pragma unroll
    for (int off = 32; off; off >>= 1) Bcand = min(Bcand, __shfl_xor(Bcand, off, 64));
    const int B = Bcand;
    __builtin_amdgcn_wave_barrier();

    // ---- pass 2: counting-sort placement of candidates (q <= B) ----
    for (int j = lane; j < NNODE; j += 64) {
        float2 pt = loc[j];
        float dx = __fsub_rn(self.x, pt.x);
        float dy = __fsub_rn(self.y, pt.y);
        float d  = __fsqrt_rn(__fadd_rn(__fmul_rn(dx, dx), __fmul_rn(dy, dy)));
        int q = (int)(d * 180.0f);
        q = q > 255 ? 255 : q;
        if (q <= B) {
            int slot = atomicAdd(&hist[w][q], 1);  // old = excl start + prior
            if (slot < 256)
                cand[w][slot] = ((uint64_t)__float_as_uint(d) << 32) | (uint32_t)j;
        }
    }
    __builtin_amdgcn_wave_barrier();
    // now hist[q] = inclusive cum (end of bin q) for all q <= B

    const int cumB = min(hist[w][B], 256);

    // ---- exact rank: start-of-bin + count of smaller keys within bin ----
    uint64_t mykey[4];
    int      myrank[4];
    #pragma unroll
    for (int s = 0; s < 4; ++s) {
        int t = lane + s * 64;
        myrank[s] = KSP + 1;                       // inactive sentinel
        if (t < cumB) {
            uint64_t k = cand[w][t];
            float d = __uint_as_float((uint32_t)(k >> 32));
            int q = (int)(d * 180.0f);
            q = q > 255 ? 255 : q;
            int start = q ? hist[w][q - 1] : 0;    // end(q-1) == start(q)
            int end   = min(hist[w][q], 256);
            int r = start;
            for (int m = start; m < end; ++m) {
                uint64_t kk = cand[w][m];
                r += (kk < k) ? 1 : 0;
            }
            mykey[s]  = k;
            myrank[s] = r;
        }
    }
    __builtin_amdgcn_wave_barrier();               // all reads done before permute writes

    // ---- in-place permute: cand[rank] = key for rank <= 200; locate self ----
    #pragma unroll
    for (int s = 0; s < 4; ++s) {
        int t = lane + s * 64;
        if (t < cumB) {
            int r = myrank[s];
            if (r <= KSP) cand[w][r] = mykey[s];
            if ((uint32_t)mykey[s] == (uint32_t)i) ssp[w] = r;   // exactly one lane
        }
    }
    __builtin_amdgcn_wave_barrier();
    const int sp = ssp[w];

    // ---- outputs: x [B*N*64] | ei0 [E] | ei1 [E] | edge_emb [E*64] ----
    const size_t E = (size_t)BATCH * NNODE * KSP;
    float* x_out = out;
    float* ei0   = out + (size_t)BATCH * NNODE * DIM;
    float* ei1   = ei0 + E;
    float* eemb  = ei1 + E;

    x_out[(size_t)node * DIM + lane] = emb[(size_t)node * DIM + lane];

    const size_t ebase = (size_t)node * KSP;
    for (int t = lane; t < KSP; t += 64) {
        int slot = t + (t >= sp ? 1 : 0);
        uint64_t kk = cand[w][slot];
        ei0[ebase + t] = (float)node;
        ei1[ebase + t] = (float)(b * NNODE + (int)(uint32_t)kk);
    }

    // per-lane W/bias registers (channel group invariant across loop)
    const int c4 = (lane & 15) << 2;
    const float4 w4 = *(const float4*)(W + c4);
    const float4 b4 = *(const float4*)(bias + c4);
    float4* em4 = (float4*)(eemb + ebase * DIM);
    for (int t = lane; t < KSP * (DIM / 4); t += 64) {
        int e    = t >> 4;
        int slot = e + (e >= sp ? 1 : 0);
        float d = __uint_as_float((uint32_t)(cand[w][slot] >> 32));
        float4 v;
        v.x = fmaf(d, w4.x, b4.x);
        v.y = fmaf(d, w4.y, b4.y);
        v.z = fmaf(d, w4.z, b4.z);
        v.w = fmaf(d, w4.w, b4.w);
        em4[t] = v;
    }
}

extern "C" void kernel_launch(void* const* d_in, const int* in_sizes, int n_in,
                              void* d_out, int out_size, void* d_ws, size_t ws_size,
                              hipStream_t stream) {
    const float* locs = (const float*)d_in[0];
    const float* emb  = (const float*)d_in[1];
    const float* W    = (const float*)d_in[2];
    const float* bias = (const float*)d_in[3];
    float* out = (float*)d_out;

    knn_edge_kernel<<<(BATCH * NNODE) / WPB, 256, 0, stream>>>(locs, emb, W, bias, out);
}